// Round 9
// baseline (384.966 us; speedup 1.0000x reference)
//
#include <hip/hip_runtime.h>
#include <hip/hip_bf16.h>

// SpatioTemporalLayer: N=8,C=256,T=120,V=25,W=5,PAD=2,H=8,CO=256,HD=32,L=125
// Round 9: (1) k_attn LDS union (Ofl overlays Vts+Pch) -> 18.9 KB, 8 blocks/CU,
//          exp2-domain softmax, 1/s folded into O;  (2) memset+prep_x+prep_w2
//          merged into one k_prep dispatch (9 -> 6 dispatches).
//  P : k_prep  (x transpose tiles | weight transposes/casts + BN params | pad zeroing)
//  G1: Y = Xrow @ w_qkv  (global_load_lds m97 structure)
//  A : per (n,t,h) fused attention + window-mean
//  G2: interR = BN1(om @ w_out + b_out + x)
//  G3: Gm = BNf(mish(interR @ W1c^T))
//  G4: d_out = BN2(Gm @ W2c^T + interR), fp32 transposed store

using bf16  = __bf16;
using bf16x8 = __bf16 __attribute__((ext_vector_type(8)));
using f32x4  = float __attribute__((ext_vector_type(4)));

#define GAS __attribute__((address_space(1)))
#define LAS __attribute__((address_space(3)))

__device__ __forceinline__ void gload_lds16(const void* g, void* l) {
  __builtin_amdgcn_global_load_lds((GAS void*)g, (LAS void*)l, 16, 0, 0);
}

// ---------------- diagnostic fallback ----------------
__global__ void k_zero(float* out, int n) {
  int i = blockIdx.x * 256 + threadIdx.x;
  if (i < n) out[i] = 0.f;
}

// ---------------- P: merged prep (x-transpose | weights | pad zero) --------
__global__ void k_prep(const float* __restrict__ x,
                       const float* __restrict__ wqkv, const float* __restrict__ wout,
                       const float* __restrict__ b_out,
                       const float* __restrict__ w1, const float* __restrict__ w2,
                       const float* __restrict__ g1, const float* __restrict__ b1,
                       const float* __restrict__ m1, const float* __restrict__ v1,
                       const float* __restrict__ gf, const float* __restrict__ bff,
                       const float* __restrict__ mf, const float* __restrict__ vf,
                       const float* __restrict__ g2, const float* __restrict__ b2,
                       const float* __restrict__ m2, const float* __restrict__ v2,
                       bf16* __restrict__ Xrow, bf16* __restrict__ WqT,
                       bf16* __restrict__ WoT, bf16* __restrict__ W1c,
                       bf16* __restrict__ W2c, float* __restrict__ pb) {
  __shared__ bf16 T[64 * 72];              // pitch 72 breaks transpose conflicts
  const int b = blockIdx.x, tid = threadIdx.x;
  if (b < 1504) {                          // ---- x transpose tile ----
    const int bx = b % 47, by = (b / 47) & 3, n = b / 188;
    const int tv0 = bx * 64, c0 = by * 64;
    const int la = tid & 63, sub = tid >> 6;
#pragma unroll 4
    for (int i = 0; i < 16; ++i) {
      int c = c0 + sub + i * 4;
      int tv = tv0 + la;
      float v = (tv < 3000) ? x[(size_t)(n * 256 + c) * 3000 + tv] : 0.f;
      T[(sub + i * 4) * 72 + la] = (bf16)v;
    }
    __syncthreads();
#pragma unroll 4
    for (int i = 0; i < 16; ++i) {
      int tvl = sub + i * 4;
      int tv = tv0 + tvl;
      if (tv < 3000)
        Xrow[(size_t)(n * 3100 + 50 + tv) * 256 + c0 + la] = T[la * 72 + tvl];
    }
  } else if (b < 3041) {                   // ---- weights + BN params ----
    int idx = (b - 1504) * 256 + tid;
    if (idx < 196608) {
      int c = idx / 768, o = idx % 768;
      WqT[o * 256 + c] = (bf16)wqkv[idx];
    } else if (idx < 262144) {
      int j = idx - 196608;
      int c = j >> 8, o = j & 255;
      WoT[o * 256 + c] = (bf16)wout[j];
    } else if (idx < 327680) {
      int j = idx - 262144;
      W1c[j] = (bf16)w1[j];
    } else if (idx < 393216) {
      int j = idx - 327680;
      W2c[j] = (bf16)w2[j];
    } else if (idx < 393472) {
      int k = idx - 393216;
      float s1 = g1[k] * rsqrtf(v1[k] + 1e-5f);
      pb[k]        = s1;
      pb[256 + k]  = b1[k] - m1[k] * s1;
      float sf = gf[k] * rsqrtf(vf[k] + 1e-5f);
      pb[512 + k]  = sf;
      pb[768 + k]  = bff[k] - mf[k] * sf;
      float s2 = g2[k] * rsqrtf(v2[k] + 1e-5f);
      pb[1024 + k] = s2;
      pb[1280 + k] = b2[k] - m2[k] * s2;
      pb[1536 + k] = b_out[k];
    }
  } else {                                 // ---- zero t-pad rows of Xrow ----
    int z = b - 3041;                      // 0..99
    int idx16 = z * 256 + tid;             // each writes 8 bf16 (16 B)
    int e0 = idx16 * 8;                    // flat pad element, 0..204799
    int pr = e0 >> 8, col = e0 & 255;      // pad row 0..799
    int n = pr / 100, r100 = pr % 100;
    int row = n * 3100 + (r100 < 50 ? r100 : 3000 + r100);
    int4 zz = {};
    *(int4*)&Xrow[(size_t)row * 256 + col] = zz;
  }
}

// ---------------- GEMM (m97 structure, global_load_lds w16) ----------------
template <int EPI>
__global__ __launch_bounds__(256, 2) void k_gemm(
    const bf16* __restrict__ A, const bf16* __restrict__ BT,
    bf16* __restrict__ Cout, int ldc, int Mreal,
    const float* __restrict__ pb, const bf16* __restrict__ Res,
    float* __restrict__ Out2) {
  __shared__ __align__(16) bf16 As[128 * 32];
  __shared__ __align__(16) bf16 Bs[128 * 32];
  const int tid = threadIdx.x;
  const int w = tid >> 6, lane = tid & 63, q = lane >> 4, l15 = lane & 15;
  const int m0 = blockIdx.x * 128, n0 = blockIdx.y * 128;
  const int wm = (w >> 1) * 64, wn = (w & 1) * 64;
  const int srow = tid >> 2;            // 0..63
  const int scol = (tid & 3) << 3;
  int ar1 = m0 + srow;        if (ar1 >= Mreal) ar1 = Mreal - 1;
  int ar2 = m0 + srow + 64;   if (ar2 >= Mreal) ar2 = Mreal - 1;
  char* ldsA = (char*)As + w * 1024;    // lane-linear dest: byte = tid*16
  char* ldsB = (char*)Bs + w * 1024;
  f32x4 acc[4][4] = {};

  for (int ks = 0; ks < 8; ++ks) {
    const bf16* ga1 = A  + (size_t)ar1 * 256 + ks * 32 + scol;
    const bf16* ga2 = A  + (size_t)ar2 * 256 + ks * 32 + scol;
    const bf16* gb  = BT + (size_t)(n0 + srow) * 256 + ks * 32 + scol;
    gload_lds16(ga1, ldsA);
    gload_lds16(ga2, ldsA + 4096);
    gload_lds16(gb,            ldsB);
    gload_lds16(gb + 64 * 256, ldsB + 4096);
    __syncthreads();
    bf16x8 af[4], bfr[4];
#pragma unroll
    for (int i = 0; i < 4; ++i) af[i]  = *(const bf16x8*)&As[(wm + i * 16 + l15) * 32 + q * 8];
#pragma unroll
    for (int i = 0; i < 4; ++i) bfr[i] = *(const bf16x8*)&Bs[(wn + i * 16 + l15) * 32 + q * 8];
#pragma unroll
    for (int i = 0; i < 4; ++i)
#pragma unroll
      for (int j = 0; j < 4; ++j)
        acc[i][j] = __builtin_amdgcn_mfma_f32_16x16x32_bf16(af[i], bfr[j], acc[i][j], 0, 0, 0);
    __syncthreads();
  }

#pragma unroll
  for (int i = 0; i < 4; ++i) {
#pragma unroll
    for (int j = 0; j < 4; ++j) {
#pragma unroll
      for (int r = 0; r < 4; ++r) {
        int row = m0 + wm + i * 16 + q * 4 + r;
        int col = n0 + wn + j * 16 + l15;
        if (row >= Mreal) continue;
        float v = acc[i][j][r];
        if constexpr (EPI == 0) {
          Cout[(size_t)row * ldc + col] = (bf16)v;
        } else if constexpr (EPI == 1) {
          v += pb[1536 + col];                       // b_out
          int n = row / 3000;                       // x residual at Xrow row+n*100+50
          v += (float)Res[(size_t)(row + n * 100 + 50) * 256 + col];
          v = v * pb[col] + pb[256 + col];          // BN1
          Cout[(size_t)row * 256 + col] = (bf16)v;
        } else if constexpr (EPI == 2) {
          float ex = __expf(v);                     // mish
          float a = 1.f + ex;
          float u = 1.f / (a * a);
          v = v * (1.f - u) / (1.f + u);
          v = v * pb[512 + col] + pb[768 + col];    // BN ffn
          Cout[(size_t)row * 256 + col] = (bf16)v;
        } else {
          v += (float)Res[(size_t)row * 256 + col]; // + interR
          v = v * pb[1024 + col] + pb[1280 + col];  // BN2
          int n = row / 3000, r2 = row - n * 3000;
          int tt = r2 / 25, vv = r2 - tt * 25;
          Out2[(size_t)((n * 256 + col) * 120 + tt) * 25 + vv] = v;   // fp32
        }
      }
    }
  }
}

// ---------------- Attention v3: LDS union, 8 blocks/CU ---------------------
__global__ __launch_bounds__(256, 8) void k_attn(const bf16* __restrict__ Y,
                                                 bf16* __restrict__ om) {
  __shared__ __align__(16) char smem[18944];       // union:
  bf16* Vts = (bf16*)smem;                         //  V^T [d][m] 32*136*2 = 8704
  bf16* Pch = (bf16*)(smem + 8704);                //  per-wave P 4*32*40*2 = 10240
  float* Ofl = (float*)smem;                       //  (after barrier) O 128*36*4
  const int tid = threadIdx.x;
  const int bi = blockIdx.x;
  const int h = bi & 7, b = bi >> 3;
  const int n = b / 120, t = b % 120;
  const bf16* Yb = Y + (size_t)(n * 3100 + t * 25) * 768 + h * 96;
  const int w = tid >> 6, lane = tid & 63, q = lane >> 4, l15 = lane & 15;

  // ---- V^T stage: wave w covers d = w*8..w*8+7; lane = m (2-way = free) ----
#pragma unroll
  for (int p = 0; p < 2; ++p) {
    int m = p * 64 + lane;
    if (m < 125) {
      int4 v4 = *(const int4*)(Yb + (size_t)m * 768 + 64 + w * 8);
      bf16x8 v8 = __builtin_bit_cast(bf16x8, v4);
#pragma unroll
      for (int jj = 0; jj < 8; ++jj) Vts[(w * 8 + jj) * 136 + m] = v8[jj];
    }
  }
  if (tid < 96) {                       // zero V pad cols m=125..127
    int d = tid / 3, m = 125 + tid % 3;
    Vts[d * 136 + m] = (bf16)0.f;
  }

  // ---- Q/K fragments direct from global (L1/L2-resident) ----
  bf16x8 qf[2];
#pragma unroll
  for (int mt = 0; mt < 2; ++mt) {
    int qrow = w * 32 + mt * 16 + l15; if (qrow > 124) qrow = 124;
    qf[mt] = *(const bf16x8*)(Yb + (size_t)qrow * 768 + q * 8);
  }
  f32x4 acc[2][8] = {};
#pragma unroll
  for (int nt = 0; nt < 8; ++nt) {
    int krow = nt * 16 + l15; if (krow > 124) krow = 124;
    bf16x8 kf = *(const bf16x8*)(Yb + (size_t)krow * 768 + 32 + q * 8);
    acc[0][nt] = __builtin_amdgcn_mfma_f32_16x16x32_bf16(qf[0], kf, acc[0][nt], 0, 0, 0);
    acc[1][nt] = __builtin_amdgcn_mfma_f32_16x16x32_bf16(qf[1], kf, acc[1][nt], 0, 0, 0);
  }
  __syncthreads();                      // Vts ready

  // ---- softmax (exp2 domain; P left unnormalized, 1/s folded into O) ----
  const float lscale = 0.0901387929f;   // (1/16) * log2(e)
  const bool maskl = (l15 >= 13);       // cols 125..127 live in nt=7
  float rinv[2][4];
#pragma unroll
  for (int mt = 0; mt < 2; ++mt) {
#pragma unroll
    for (int r = 0; r < 4; ++r) {
      float mx = -1e30f;
#pragma unroll
      for (int nt = 0; nt < 8; ++nt) {
        float xv = acc[mt][nt][r] * lscale;
        if (nt == 7 && maskl) xv = -1e30f;
        acc[mt][nt][r] = xv;
        mx = fmaxf(mx, xv);
      }
#pragma unroll
      for (int d = 1; d < 16; d <<= 1) mx = fmaxf(mx, __shfl_xor(mx, d, 64));
      float s = 0.f;
#pragma unroll
      for (int nt = 0; nt < 8; ++nt) {
        float pz = exp2f(acc[mt][nt][r] - mx);
        acc[mt][nt][r] = pz; s += pz;
      }
#pragma unroll
      for (int d = 1; d < 16; d <<= 1) s += __shfl_xor(s, d, 64);
      rinv[mt][r] = 1.f / s;
    }
  }

  // ---- PV via per-wave P chunks (wave-local, no barriers) ----
  f32x4 oacc[2][2] = {};
  bf16* pw = &Pch[w * (32 * 40)];
#pragma unroll
  for (int ks = 0; ks < 4; ++ks) {
#pragma unroll
    for (int mt = 0; mt < 2; ++mt)
#pragma unroll
      for (int r = 0; r < 4; ++r)
#pragma unroll
        for (int c = 0; c < 2; ++c)
          pw[(mt * 16 + q * 4 + r) * 40 + c * 16 + l15] = (bf16)acc[mt][2 * ks + c][r];
    bf16x8 vf0 = *(const bf16x8*)&Vts[l15 * 136 + ks * 32 + q * 8];
    bf16x8 vf1 = *(const bf16x8*)&Vts[(16 + l15) * 136 + ks * 32 + q * 8];
#pragma unroll
    for (int mt = 0; mt < 2; ++mt) {
      bf16x8 af = *(const bf16x8*)&pw[(mt * 16 + l15) * 40 + q * 8];
      oacc[mt][0] = __builtin_amdgcn_mfma_f32_16x16x32_bf16(af, vf0, oacc[mt][0], 0, 0, 0);
      oacc[mt][1] = __builtin_amdgcn_mfma_f32_16x16x32_bf16(af, vf1, oacc[mt][1], 0, 0, 0);
    }
  }
#pragma unroll
  for (int mt = 0; mt < 2; ++mt)        // fold softmax denominator
#pragma unroll
    for (int nd = 0; nd < 2; ++nd)
#pragma unroll
      for (int r = 0; r < 4; ++r)
        oacc[mt][nd][r] *= rinv[mt][r];

  __syncthreads();                      // all Vts/Pch reads done before overlay
#pragma unroll
  for (int mt = 0; mt < 2; ++mt)
#pragma unroll
    for (int nd = 0; nd < 2; ++nd)
#pragma unroll
      for (int r = 0; r < 4; ++r)
        Ofl[(w * 32 + mt * 16 + q * 4 + r) * 36 + nd * 16 + l15] = oacc[mt][nd][r];
  __syncthreads();
  // mean over W (5 rows) -> om[(n,t,v)][h*32+d], already /5
  bf16* dst = om + (size_t)((n * 120 + t) * 25) * 256 + h * 32;
  for (int j = tid; j < 800; j += 256) {
    int vv = j >> 5, d = j & 31;
    float s = 0.f;
#pragma unroll
    for (int ww = 0; ww < 5; ++ww) s += Ofl[(ww * 25 + vv) * 36 + d];
    dst[vv * 256 + d] = (bf16)(s * 0.2f);
  }
}

// ---------------- launch ----------------
extern "C" void kernel_launch(void* const* d_in, const int* in_sizes, int n_in,
                              void* d_out, int out_size, void* d_ws, size_t ws_size,
                              hipStream_t stream) {
  const size_t NEED = 51584000;
  if (ws_size < NEED) {
    k_zero<<<(out_size + 255) / 256, 256, 0, stream>>>((float*)d_out, out_size);
    return;
  }
  const float* x     = (const float*)d_in[0];
  const float* wqkv  = (const float*)d_in[1];
  const float* wout  = (const float*)d_in[2];
  const float* b_out = (const float*)d_in[3];
  const float* bn1_g = (const float*)d_in[4];
  const float* bn1_b = (const float*)d_in[5];
  const float* ffn_w1= (const float*)d_in[6];
  const float* ffn_w2= (const float*)d_in[7];
  const float* ffn_g = (const float*)d_in[8];
  const float* ffn_b = (const float*)d_in[9];
  const float* bn2_g = (const float*)d_in[10];
  const float* bn2_b = (const float*)d_in[11];
  const float* bn1_m = (const float*)d_in[12];
  const float* bn1_v = (const float*)d_in[13];
  const float* ffn_m = (const float*)d_in[14];
  const float* ffn_v = (const float*)d_in[15];
  const float* bn2_m = (const float*)d_in[16];
  const float* bn2_v = (const float*)d_in[17];

  char* ws = (char*)d_ws;
  float* pb    = (float*)(ws + 0);           // 7,168
  bf16* WqT    = (bf16*)(ws + 7168);         // 393,216
  bf16* WoT    = (bf16*)(ws + 400384);       // 131,072
  bf16* W1c    = (bf16*)(ws + 531456);       // 131,072
  bf16* W2c    = (bf16*)(ws + 662528);       // 131,072
  bf16* Xrow   = (bf16*)(ws + 793600);       // 12,697,600
  bf16* Y      = (bf16*)(ws + 13491200);     // 38,092,800 -> 51,584,000
  bf16* interR = Y;                          // alias: Y dead after attention
  bf16* Gm     = (bf16*)(ws + 25779200);     // inside Y, disjoint from interR
  bf16* om     = (bf16*)d_out;               // first half of fp32 out buffer

  k_prep<<<3141, 256, 0, stream>>>(x, wqkv, wout, b_out, ffn_w1, ffn_w2,
                                   bn1_g, bn1_b, bn1_m, bn1_v,
                                   ffn_g, ffn_b, ffn_m, ffn_v,
                                   bn2_g, bn2_b, bn2_m, bn2_v,
                                   Xrow, WqT, WoT, W1c, W2c, pb);
  k_gemm<0><<<dim3(194, 6), 256, 0, stream>>>(Xrow, WqT, Y, 768, 24800, pb, nullptr, nullptr);
  k_attn<<<7680, 256, 0, stream>>>(Y, om);
  k_gemm<1><<<dim3(188, 2), 256, 0, stream>>>(om, WoT, interR, 256, 24000, pb, Xrow, nullptr);
  k_gemm<2><<<dim3(188, 2), 256, 0, stream>>>(interR, W1c, Gm, 256, 24000, pb, nullptr, nullptr);
  k_gemm<3><<<dim3(188, 2), 256, 0, stream>>>(Gm, W2c, nullptr, 256, 24000, pb, interR, (float*)d_out);
}

// Round 10
// 252.399 us; speedup vs baseline: 1.5252x; 1.5252x over previous
//
#include <hip/hip_runtime.h>
#include <hip/hip_bf16.h>

// SpatioTemporalLayer: N=8,C=256,T=120,V=25,W=5,PAD=2,H=8,CO=256,HD=32,L=125
// Round 10: (1) k_attn back to 4 blocks/CU (R9's (256,8) forced 64-reg budget
//           -> spills -> 767MB scratch traffic). Keep LDS union + exp2 softmax
//           + rinv-fold; DROP max-subtraction (scores bounded, fp32-safe).
//           (2) EPI3: LDS-transposed coalesced fp32 store (was fully scattered).
//  P : k_prep  (x transpose tiles | weights + BN params | pad zeroing)
//  G1: Y = Xrow @ w_qkv  (global_load_lds m97 structure)
//  A : per (n,t,h) fused attention + window-mean
//  G2: interR = BN1(om @ w_out + b_out + x)
//  G3: Gm = BNf(mish(interR @ W1c^T))
//  G4: d_out = BN2(Gm @ W2c^T + interR), LDS-transposed coalesced store

using bf16  = __bf16;
using bf16x8 = __bf16 __attribute__((ext_vector_type(8)));
using f32x4  = float __attribute__((ext_vector_type(4)));

#define GAS __attribute__((address_space(1)))
#define LAS __attribute__((address_space(3)))

__device__ __forceinline__ void gload_lds16(const void* g, void* l) {
  __builtin_amdgcn_global_load_lds((GAS void*)g, (LAS void*)l, 16, 0, 0);
}

// ---------------- diagnostic fallback ----------------
__global__ void k_zero(float* out, int n) {
  int i = blockIdx.x * 256 + threadIdx.x;
  if (i < n) out[i] = 0.f;
}

// ---------------- P: merged prep (x-transpose | weights | pad zero) --------
__global__ void k_prep(const float* __restrict__ x,
                       const float* __restrict__ wqkv, const float* __restrict__ wout,
                       const float* __restrict__ b_out,
                       const float* __restrict__ w1, const float* __restrict__ w2,
                       const float* __restrict__ g1, const float* __restrict__ b1,
                       const float* __restrict__ m1, const float* __restrict__ v1,
                       const float* __restrict__ gf, const float* __restrict__ bff,
                       const float* __restrict__ mf, const float* __restrict__ vf,
                       const float* __restrict__ g2, const float* __restrict__ b2,
                       const float* __restrict__ m2, const float* __restrict__ v2,
                       bf16* __restrict__ Xrow, bf16* __restrict__ WqT,
                       bf16* __restrict__ WoT, bf16* __restrict__ W1c,
                       bf16* __restrict__ W2c, float* __restrict__ pb) {
  __shared__ bf16 T[64 * 72];              // pitch 72 breaks transpose conflicts
  const int b = blockIdx.x, tid = threadIdx.x;
  if (b < 1504) {                          // ---- x transpose tile ----
    const int bx = b % 47, by = (b / 47) & 3, n = b / 188;
    const int tv0 = bx * 64, c0 = by * 64;
    const int la = tid & 63, sub = tid >> 6;
#pragma unroll 4
    for (int i = 0; i < 16; ++i) {
      int c = c0 + sub + i * 4;
      int tv = tv0 + la;
      float v = (tv < 3000) ? x[(size_t)(n * 256 + c) * 3000 + tv] : 0.f;
      T[(sub + i * 4) * 72 + la] = (bf16)v;
    }
    __syncthreads();
#pragma unroll 4
    for (int i = 0; i < 16; ++i) {
      int tvl = sub + i * 4;
      int tv = tv0 + tvl;
      if (tv < 3000)
        Xrow[(size_t)(n * 3100 + 50 + tv) * 256 + c0 + la] = T[la * 72 + tvl];
    }
  } else if (b < 3041) {                   // ---- weights + BN params ----
    int idx = (b - 1504) * 256 + tid;
    if (idx < 196608) {
      int c = idx / 768, o = idx % 768;
      WqT[o * 256 + c] = (bf16)wqkv[idx];
    } else if (idx < 262144) {
      int j = idx - 196608;
      int c = j >> 8, o = j & 255;
      WoT[o * 256 + c] = (bf16)wout[j];
    } else if (idx < 327680) {
      int j = idx - 262144;
      W1c[j] = (bf16)w1[j];
    } else if (idx < 393216) {
      int j = idx - 327680;
      W2c[j] = (bf16)w2[j];
    } else if (idx < 393472) {
      int k = idx - 393216;
      float s1 = g1[k] * rsqrtf(v1[k] + 1e-5f);
      pb[k]        = s1;
      pb[256 + k]  = b1[k] - m1[k] * s1;
      float sf = gf[k] * rsqrtf(vf[k] + 1e-5f);
      pb[512 + k]  = sf;
      pb[768 + k]  = bff[k] - mf[k] * sf;
      float s2 = g2[k] * rsqrtf(v2[k] + 1e-5f);
      pb[1024 + k] = s2;
      pb[1280 + k] = b2[k] - m2[k] * s2;
      pb[1536 + k] = b_out[k];
    }
  } else {                                 // ---- zero t-pad rows of Xrow ----
    int z = b - 3041;                      // 0..99
    int idx16 = z * 256 + tid;             // each writes 8 bf16 (16 B)
    int e0 = idx16 * 8;
    int pr = e0 >> 8, col = e0 & 255;      // pad row 0..799
    int n = pr / 100, r100 = pr % 100;
    int row = n * 3100 + (r100 < 50 ? r100 : 3000 + r100);
    int4 zz = {};
    *(int4*)&Xrow[(size_t)row * 256 + col] = zz;
  }
}

// ---------------- GEMM (m97 structure, global_load_lds w16) ----------------
template <int EPI>
__global__ __launch_bounds__(256, 2) void k_gemm(
    const bf16* __restrict__ A, const bf16* __restrict__ BT,
    bf16* __restrict__ Cout, int ldc, int Mreal,
    const float* __restrict__ pb, const bf16* __restrict__ Res,
    float* __restrict__ Out2) {
  __shared__ __align__(16) char smem[19456];   // As|Bs (16K) U Tt (2x128x19 f32)
  bf16* As = (bf16*)smem;
  bf16* Bs = (bf16*)(smem + 8192);
  const int tid = threadIdx.x;
  const int w = tid >> 6, lane = tid & 63, q = lane >> 4, l15 = lane & 15;
  const int m0 = blockIdx.x * 128, n0 = blockIdx.y * 128;
  const int wm = (w >> 1) * 64, wn = (w & 1) * 64;
  const int srow = tid >> 2;            // 0..63
  const int scol = (tid & 3) << 3;
  int ar1 = m0 + srow;        if (ar1 >= Mreal) ar1 = Mreal - 1;
  int ar2 = m0 + srow + 64;   if (ar2 >= Mreal) ar2 = Mreal - 1;
  char* ldsA = (char*)As + w * 1024;    // lane-linear dest: byte = tid*16
  char* ldsB = (char*)Bs + w * 1024;
  f32x4 acc[4][4] = {};

  for (int ks = 0; ks < 8; ++ks) {
    const bf16* ga1 = A  + (size_t)ar1 * 256 + ks * 32 + scol;
    const bf16* ga2 = A  + (size_t)ar2 * 256 + ks * 32 + scol;
    const bf16* gb  = BT + (size_t)(n0 + srow) * 256 + ks * 32 + scol;
    gload_lds16(ga1, ldsA);
    gload_lds16(ga2, ldsA + 4096);
    gload_lds16(gb,            ldsB);
    gload_lds16(gb + 64 * 256, ldsB + 4096);
    __syncthreads();
    bf16x8 af[4], bfr[4];
#pragma unroll
    for (int i = 0; i < 4; ++i) af[i]  = *(const bf16x8*)&As[(wm + i * 16 + l15) * 32 + q * 8];
#pragma unroll
    for (int i = 0; i < 4; ++i) bfr[i] = *(const bf16x8*)&Bs[(wn + i * 16 + l15) * 32 + q * 8];
#pragma unroll
    for (int i = 0; i < 4; ++i)
#pragma unroll
      for (int j = 0; j < 4; ++j)
        acc[i][j] = __builtin_amdgcn_mfma_f32_16x16x32_bf16(af[i], bfr[j], acc[i][j], 0, 0, 0);
    __syncthreads();
  }

  if constexpr (EPI != 3) {
#pragma unroll
    for (int i = 0; i < 4; ++i) {
#pragma unroll
      for (int j = 0; j < 4; ++j) {
#pragma unroll
        for (int r = 0; r < 4; ++r) {
          int row = m0 + wm + i * 16 + q * 4 + r;
          int col = n0 + wn + j * 16 + l15;
          if (row >= Mreal) continue;
          float v = acc[i][j][r];
          if constexpr (EPI == 0) {
            Cout[(size_t)row * ldc + col] = (bf16)v;
          } else if constexpr (EPI == 1) {
            v += pb[1536 + col];                       // b_out
            int n = row / 3000;                       // x residual at Xrow row+n*100+50
            v += (float)Res[(size_t)(row + n * 100 + 50) * 256 + col];
            v = v * pb[col] + pb[256 + col];          // BN1
            Cout[(size_t)row * 256 + col] = (bf16)v;
          } else {                                    // EPI == 2
            float ex = __expf(v);                     // mish
            float a = 1.f + ex;
            float u = 1.f / (a * a);
            v = v * (1.f - u) / (1.f + u);
            v = v * pb[512 + col] + pb[768 + col];    // BN ffn
            Cout[(size_t)row * 256 + col] = (bf16)v;
          }
        }
      }
    }
  } else {
    // EPI3: +interR residual, BN2, LDS-transposed coalesced fp32 store
    float* Tt = (float*)smem;              // 2 tiles of 128 x pitch-19 fp32
    const int tti = (w & 1);               // wave's col-half
#pragma unroll
    for (int jj = 0; jj < 4; ++jj) {
      __syncthreads();                     // previous phase's Tt reads done
#pragma unroll
      for (int i = 0; i < 4; ++i) {
#pragma unroll
        for (int r = 0; r < 4; ++r) {
          int rowl = wm + i * 16 + q * 4 + r;
          int row = m0 + rowl;
          int col = n0 + tti * 64 + jj * 16 + l15;
          float v = acc[i][jj][r];
          v += (float)Res[(size_t)row * 256 + col];   // + interR (in-bounds alloc)
          v = v * pb[1024 + col] + pb[1280 + col];    // BN2
          Tt[tti * 2432 + rowl * 19 + l15] = v;
        }
      }
      __syncthreads();
#pragma unroll
      for (int k = 0; k < 16; ++k) {
        int flat = k * 256 + tid;          // 4096 values
        int tt2 = flat >> 11;
        int rem = flat & 2047;
        int colL = rem >> 7;
        int rowl = rem & 127;
        int row = m0 + rowl;
        if (row < Mreal) {
          int col = n0 + tt2 * 64 + jj * 16 + colL;
          int n = row / 3000, r2 = row - n * 3000;
          Out2[(size_t)(n * 256 + col) * 3000 + r2] = Tt[tt2 * 2432 + rowl * 19 + colL];
        }
      }
    }
  }
}

// ---------------- Attention v4: 4 blocks/CU (register-bound), lean softmax --
__global__ __launch_bounds__(256, 4) void k_attn(const bf16* __restrict__ Y,
                                                 bf16* __restrict__ om) {
  __shared__ __align__(16) char smem[18944];       // union:
  bf16* Vts = (bf16*)smem;                         //  V^T [d][m] 32*136*2 = 8704
  bf16* Pch = (bf16*)(smem + 8704);                //  per-wave P 4*32*40*2 = 10240
  float* Ofl = (float*)smem;                       //  (after barrier) O 128*36*4
  const int tid = threadIdx.x;
  const int bi = blockIdx.x;
  const int h = bi & 7, b = bi >> 3;
  const int n = b / 120, t = b % 120;
  const bf16* Yb = Y + (size_t)(n * 3100 + t * 25) * 768 + h * 96;
  const int w = tid >> 6, lane = tid & 63, q = lane >> 4, l15 = lane & 15;

  // ---- V^T stage: wave w covers d = w*8..w*8+7; lane = m (2-way = free) ----
#pragma unroll
  for (int p = 0; p < 2; ++p) {
    int m = p * 64 + lane;
    if (m < 125) {
      int4 v4 = *(const int4*)(Yb + (size_t)m * 768 + 64 + w * 8);
      bf16x8 v8 = __builtin_bit_cast(bf16x8, v4);
#pragma unroll
      for (int jj = 0; jj < 8; ++jj) Vts[(w * 8 + jj) * 136 + m] = v8[jj];
    }
  }
  if (tid < 96) {                       // zero V pad cols m=125..127
    int d = tid / 3, m = 125 + tid % 3;
    Vts[d * 136 + m] = (bf16)0.f;
  }

  // ---- Q/K fragments direct from global (L1/L2-resident) ----
  bf16x8 qf[2];
#pragma unroll
  for (int mt = 0; mt < 2; ++mt) {
    int qrow = w * 32 + mt * 16 + l15; if (qrow > 124) qrow = 124;
    qf[mt] = *(const bf16x8*)(Yb + (size_t)qrow * 768 + q * 8);
  }
  f32x4 acc[2][8] = {};
#pragma unroll
  for (int nt = 0; nt < 8; ++nt) {
    int krow = nt * 16 + l15; if (krow > 124) krow = 124;
    bf16x8 kf = *(const bf16x8*)(Yb + (size_t)krow * 768 + 32 + q * 8);
    acc[0][nt] = __builtin_amdgcn_mfma_f32_16x16x32_bf16(qf[0], kf, acc[0][nt], 0, 0, 0);
    acc[1][nt] = __builtin_amdgcn_mfma_f32_16x16x32_bf16(qf[1], kf, acc[1][nt], 0, 0, 0);
  }
  __syncthreads();                      // Vts ready

  // ---- softmax, exp2 domain, NO max-sub (scores bounded; fp32-safe),
  //      P left unnormalized, 1/s folded into O ----
  const float lscale = 0.0901387929f;   // (1/16) * log2(e)
  const bool maskl = (l15 >= 13);       // cols 125..127 live in nt=7
  float rinv[2][4];
#pragma unroll
  for (int mt = 0; mt < 2; ++mt) {
#pragma unroll
    for (int r = 0; r < 4; ++r) {
      float s = 0.f;
#pragma unroll
      for (int nt = 0; nt < 8; ++nt) {
        float xv = acc[mt][nt][r] * lscale;
        if (nt == 7 && maskl) xv = -1e30f;     // exp2 -> 0
        float pz = exp2f(xv);
        acc[mt][nt][r] = pz; s += pz;
      }
#pragma unroll
      for (int d = 1; d < 16; d <<= 1) s += __shfl_xor(s, d, 64);
      rinv[mt][r] = 1.f / s;
    }
  }

  // ---- PV via per-wave P chunks (wave-local, no barriers) ----
  f32x4 oacc[2][2] = {};
  bf16* pw = &Pch[w * (32 * 40)];
#pragma unroll
  for (int ks = 0; ks < 4; ++ks) {
#pragma unroll
    for (int mt = 0; mt < 2; ++mt)
#pragma unroll
      for (int r = 0; r < 4; ++r)
#pragma unroll
        for (int c = 0; c < 2; ++c)
          pw[(mt * 16 + q * 4 + r) * 40 + c * 16 + l15] = (bf16)acc[mt][2 * ks + c][r];
    bf16x8 vf0 = *(const bf16x8*)&Vts[l15 * 136 + ks * 32 + q * 8];
    bf16x8 vf1 = *(const bf16x8*)&Vts[(16 + l15) * 136 + ks * 32 + q * 8];
#pragma unroll
    for (int mt = 0; mt < 2; ++mt) {
      bf16x8 af = *(const bf16x8*)&pw[(mt * 16 + l15) * 40 + q * 8];
      oacc[mt][0] = __builtin_amdgcn_mfma_f32_16x16x32_bf16(af, vf0, oacc[mt][0], 0, 0, 0);
      oacc[mt][1] = __builtin_amdgcn_mfma_f32_16x16x32_bf16(af, vf1, oacc[mt][1], 0, 0, 0);
    }
  }
#pragma unroll
  for (int mt = 0; mt < 2; ++mt)        // fold softmax denominator
#pragma unroll
    for (int nd = 0; nd < 2; ++nd)
#pragma unroll
      for (int r = 0; r < 4; ++r)
        oacc[mt][nd][r] *= rinv[mt][r];

  __syncthreads();                      // all Vts/Pch reads done before overlay
#pragma unroll
  for (int mt = 0; mt < 2; ++mt)
#pragma unroll
    for (int nd = 0; nd < 2; ++nd)
#pragma unroll
      for (int r = 0; r < 4; ++r)
        Ofl[(w * 32 + mt * 16 + q * 4 + r) * 36 + nd * 16 + l15] = oacc[mt][nd][r];
  __syncthreads();
  // mean over W (5 rows) -> om[(n,t,v)][h*32+d], already /5
  bf16* dst = om + (size_t)((n * 120 + t) * 25) * 256 + h * 32;
  for (int j = tid; j < 800; j += 256) {
    int vv = j >> 5, d = j & 31;
    float s = 0.f;
#pragma unroll
    for (int ww = 0; ww < 5; ++ww) s += Ofl[(ww * 25 + vv) * 36 + d];
    dst[vv * 256 + d] = (bf16)(s * 0.2f);
  }
}

// ---------------- launch ----------------
extern "C" void kernel_launch(void* const* d_in, const int* in_sizes, int n_in,
                              void* d_out, int out_size, void* d_ws, size_t ws_size,
                              hipStream_t stream) {
  const size_t NEED = 51584000;
  if (ws_size < NEED) {
    k_zero<<<(out_size + 255) / 256, 256, 0, stream>>>((float*)d_out, out_size);
    return;
  }
  const float* x     = (const float*)d_in[0];
  const float* wqkv  = (const float*)d_in[1];
  const float* wout  = (const float*)d_in[2];
  const float* b_out = (const float*)d_in[3];
  const float* bn1_g = (const float*)d_in[4];
  const float* bn1_b = (const float*)d_in[5];
  const float* ffn_w1= (const float*)d_in[6];
  const float* ffn_w2= (const float*)d_in[7];
  const float* ffn_g = (const float*)d_in[8];
  const float* ffn_b = (const float*)d_in[9];
  const float* bn2_g = (const float*)d_in[10];
  const float* bn2_b = (const float*)d_in[11];
  const float* bn1_m = (const float*)d_in[12];
  const float* bn1_v = (const float*)d_in[13];
  const float* ffn_m = (const float*)d_in[14];
  const float* ffn_v = (const float*)d_in[15];
  const float* bn2_m = (const float*)d_in[16];
  const float* bn2_v = (const float*)d_in[17];

  char* ws = (char*)d_ws;
  float* pb    = (float*)(ws + 0);           // 7,168
  bf16* WqT    = (bf16*)(ws + 7168);         // 393,216
  bf16* WoT    = (bf16*)(ws + 400384);       // 131,072
  bf16* W1c    = (bf16*)(ws + 531456);       // 131,072
  bf16* W2c    = (bf16*)(ws + 662528);       // 131,072
  bf16* Xrow   = (bf16*)(ws + 793600);       // 12,697,600
  bf16* Y      = (bf16*)(ws + 13491200);     // 38,092,800 -> 51,584,000
  bf16* interR = Y;                          // alias: Y dead after attention
  bf16* Gm     = (bf16*)(ws + 25779200);     // inside Y, disjoint from interR
  bf16* om     = (bf16*)d_out;               // first half of fp32 out buffer

  k_prep<<<3141, 256, 0, stream>>>(x, wqkv, wout, b_out, ffn_w1, ffn_w2,
                                   bn1_g, bn1_b, bn1_m, bn1_v,
                                   ffn_g, ffn_b, ffn_m, ffn_v,
                                   bn2_g, bn2_b, bn2_m, bn2_v,
                                   Xrow, WqT, WoT, W1c, W2c, pb);
  k_gemm<0><<<dim3(194, 6), 256, 0, stream>>>(Xrow, WqT, Y, 768, 24800, pb, nullptr, nullptr);
  k_attn<<<7680, 256, 0, stream>>>(Y, om);
  k_gemm<1><<<dim3(188, 2), 256, 0, stream>>>(om, WoT, interR, 256, 24000, pb, Xrow, nullptr);
  k_gemm<2><<<dim3(188, 2), 256, 0, stream>>>(interR, W1c, Gm, 256, 24000, pb, nullptr, nullptr);
  k_gemm<3><<<dim3(188, 2), 256, 0, stream>>>(Gm, W2c, nullptr, 256, 24000, pb, interR, (float*)d_out);
}